// Round 14
// baseline (309.146 us; speedup 1.0000x reference)
//
#include <hip/hip_runtime.h>
#include <cmath>

// Problem constants
constexpr int BB = 4, LL = 8, NPTS = 4096, MQ = 1024, KNNK = 16;
constexpr int C1 = 64, C2 = 128;
constexpr int NSLICE = BB * LL;                       // 32
constexpr long long SAMP = (long long)NSLICE * MQ * KNNK;  // 524288 samples
constexpr int NBLK_ZZ = 512;
constexpr int ZZW = C1 * C1 + C1;                     // 4160 (full 64x64 + sum_z)

// Workspace layout (bytes)
constexpr size_t OFF_G    = 0;                                   // float4[SAMP] = 8 MB
constexpr size_t OFF_GMOM = (size_t)8 * 1024 * 1024;             // float[512*9]
constexpr size_t OFF_S1   = OFF_GMOM + 20480;                    // float[128]: scale1,shift1
constexpr size_t OFF_ZZP  = OFF_S1 + 1024;                       // float[NBLK_ZZ*ZZW]
constexpr size_t OFF_ZZS  = OFF_ZZP + (size_t)NBLK_ZZ * ZZW * 4; // double[ZZW]
constexpr size_t OFF_S2   = OFF_ZZS + (size_t)ZZW * 8;           // float[256]: scale2,shift2
// W2 hi/lo bf16 splits: reuse the zzp region (dead after zzred, before stats2)
constexpr size_t OFF_W2H  = OFF_ZZP;                             // ushort[8192]
constexpr size_t OFF_W2L  = OFF_ZZP + 16384;                     // ushort[8192]
constexpr size_t OFF_CNT  = OFF_S2 + 1024;                       // int[1]

typedef __attribute__((ext_vector_type(8))) short short8_b;   // 8 bf16 (4 VGPRs)
typedef __attribute__((ext_vector_type(4))) float f32x4;

__device__ inline ushort f2bf(float f) {        // RNE float -> bf16 bits
  unsigned u = __float_as_uint(f);
  return (ushort)((u + 0x7fffu + ((u >> 16) & 1u)) >> 16);
}

// DPP row_shr:1 within 16-lane rows (segments ARE rows). Row-head lanes keep
// the literal-0 'old' (bound_ctrl=false) and are overridden by the segHead fix.
__device__ inline float dpp_shr1_f(float x) {
  return __uint_as_float((unsigned)__builtin_amdgcn_update_dpp(
      0, (int)__float_as_uint(x), 0x111, 0xF, 0xF, false));
}
__device__ inline int dpp_shr1_i(int x) {
  return __builtin_amdgcn_update_dpp(0, x, 0x111, 0xF, 0xF, false);
}

// ---------------------------------------------------------------------------
// K1: per-slice KNN + gather + fused coordinate moments + fused stats1 (the
// LAST block to finish computes BN1 stats from the completed gmom array —
// canonical threadfence+atomic last-block pattern; s1 value is independent of
// which block runs it, so the result is deterministic). KNN core is the R11
// best-measured form: bitonic seed, branchy pops with __shfl broadcasts, DPP
// row_shr:1 shift-insert. 512 blocks x 1024 threads.
// ---------------------------------------------------------------------------
__global__ __launch_bounds__(1024, 8) void knn_kernel(const float* __restrict__ pts,
                                                      const float* __restrict__ qrs,
                                                      float4* __restrict__ G,
                                                      float* __restrict__ gmom,
                                                      const float* __restrict__ W1,
                                                      const float* __restrict__ b1,
                                                      const float* __restrict__ g1,
                                                      const float* __restrict__ be1,
                                                      float* __restrict__ s1out,
                                                      int* __restrict__ cnt)
{
#pragma clang fp contract(off)
  __shared__ float4 sp[NPTS];   // (x,y,z,p2) = 64 KB
  __shared__ float smom[16][9];
  __shared__ double mstat[9];
  __shared__ bool lastBlk;
  const int tid = threadIdx.x;
  const int bl = blockIdx.x >> 4;    // slice (32)
  const int qt = blockIdx.x & 15;    // 16 query tiles of 64
  const int wave = tid >> 6;
  const int lane = tid & 63;
  const float INF = 3.402823466e38f;

  const float* pb = pts + (size_t)bl * NPTS * 3;
  for (int p = tid; p < NPTS; p += 1024) {
    float x = pb[p * 3 + 0], y = pb[p * 3 + 1], z = pb[p * 3 + 2];
    float pp = (x * x + y * y) + z * z;       // plain rounding
    sp[p] = make_float4(x, y, z, pp);
  }
  __syncthreads();

  const int qbase = qt * 64 + wave * 4;
  const float* qp = qrs + ((size_t)bl * MQ + qbase) * 3;
  const float qxA = qp[0], qyA = qp[1], qzA = qp[2];
  const float qxB = qp[3], qyB = qp[4], qzB = qp[5];
  const float qxC = qp[6], qyC = qp[7], qzC = qp[8];
  const float qxD = qp[9], qyD = qp[10], qzD = qp[11];
  const float q2A = (qxA * qxA + qyA * qyA) + qzA * qzA;   // plain rounding
  const float q2B = (qxB * qxB + qyB * qyB) + qzB * qzB;
  const float q2C = (qxC * qxC + qyC * qyC) + qzC * qzC;
  const float q2D = (qxD * qxD + qyD * qyD) + qzD * qzD;

  const int seg = lane >> 4;
  const bool segHead = (lane & 15) == 0;

  float Ld; int Li;
  float tauA, tauB, tauC, tauD;

  // ---- seed (i = 0): bitonic sort of 64 (d, lane) keys per query ----
  {
    float4 P = sp[lane];
    float pqA = fmaf(P.z, qzA, fmaf(P.y, qyA, P.x * qxA));
    float pqB = fmaf(P.z, qzB, fmaf(P.y, qyB, P.x * qxB));
    float pqC = fmaf(P.z, qzC, fmaf(P.y, qyC, P.x * qxC));
    float pqD = fmaf(P.z, qzD, fmaf(P.y, qyD, P.x * qxD));
    float dA = fmaf(-2.0f, pqA, q2A + P.w);
    float dB = fmaf(-2.0f, pqB, q2B + P.w);
    float dC = fmaf(-2.0f, pqC, q2C + P.w);
    float dD = fmaf(-2.0f, pqD, q2D + P.w);

    unsigned uA = __float_as_uint(dA); uA = (uA & 0x80000000u) ? ~uA : (uA | 0x80000000u);
    unsigned uB = __float_as_uint(dB); uB = (uB & 0x80000000u) ? ~uB : (uB | 0x80000000u);
    unsigned uC = __float_as_uint(dC); uC = (uC & 0x80000000u) ? ~uC : (uC | 0x80000000u);
    unsigned uD = __float_as_uint(dD); uD = (uD & 0x80000000u) ? ~uD : (uD | 0x80000000u);
    unsigned long long kA = ((unsigned long long)uA << 6) | (unsigned)lane;
    unsigned long long kB = ((unsigned long long)uB << 6) | (unsigned)lane;
    unsigned long long kC = ((unsigned long long)uC << 6) | (unsigned)lane;
    unsigned long long kD = ((unsigned long long)uD << 6) | (unsigned)lane;

#pragma unroll
    for (int k = 2; k <= 64; k <<= 1) {
#pragma unroll
      for (int j = k >> 1; j >= 1; j >>= 1) {
        const bool selMin = ((lane & j) == 0) == ((lane & k) == 0);
        unsigned long long pA = __shfl_xor(kA, j, 64);
        unsigned long long pB = __shfl_xor(kB, j, 64);
        unsigned long long pC = __shfl_xor(kC, j, 64);
        unsigned long long pD = __shfl_xor(kD, j, 64);
        kA = ((kA < pA) == selMin) ? kA : pA;
        kB = ((kB < pB) == selMin) ? kB : pB;
        kC = ((kC < pC) == selMin) ? kC : pC;
        kD = ((kD < pD) == selMin) ? kD : pD;
      }
    }

    const int src = lane & 15;
    unsigned long long rA = __shfl(kA, src, 64);
    unsigned long long rB = __shfl(kB, src, 64);
    unsigned long long rC = __shfl(kC, src, 64);
    unsigned long long rD = __shfl(kD, src, 64);
    unsigned long long r0 = (seg & 1) ? rB : rA;
    unsigned long long r1 = (seg & 1) ? rD : rC;
    unsigned long long rr = (seg & 2) ? r1 : r0;
    unsigned um = (unsigned)(rr >> 6);
    um = (um & 0x80000000u) ? (um & 0x7fffffffu) : ~um;    // inverse map
    Ld = __uint_as_float(um);
    Li = (int)(rr & 63u);
    tauA = __shfl(Ld, 15, 64);
    tauB = __shfl(Ld, 31, 64);
    tauC = __shfl(Ld, 47, 64);
    tauD = __shfl(Ld, 63, 64);
  }

  // ---- main scan: i = 1..63 ----
  for (int i = 1; i < 64; ++i) {
    float4 P = sp[i * 64 + lane];
    float pqA = fmaf(P.z, qzA, fmaf(P.y, qyA, P.x * qxA));
    float pqB = fmaf(P.z, qzB, fmaf(P.y, qyB, P.x * qxB));
    float pqC = fmaf(P.z, qzC, fmaf(P.y, qyC, P.x * qxC));
    float pqD = fmaf(P.z, qzD, fmaf(P.y, qyD, P.x * qxD));
    float dA = fmaf(-2.0f, pqA, q2A + P.w);
    float dB = fmaf(-2.0f, pqB, q2B + P.w);
    float dC = fmaf(-2.0f, pqC, q2C + P.w);
    float dD = fmaf(-2.0f, pqD, q2D + P.w);

    unsigned long long mA = __ballot(dA < tauA);
    unsigned long long mB = __ballot(dB < tauB);
    unsigned long long mC = __ballot(dC < tauC);
    unsigned long long mD = __ballot(dD < tauD);

    if (mA | mB | mC | mD) {
      do {
        float vA = INF, vB = INF, vC = INF, vD = INF;
        int iA = 0, iB = 0, iC = 0, iD = 0;
        if (mA) { int b = (int)__builtin_ctzll(mA); mA &= mA - 1;
                  vA = __shfl(dA, b, 64); iA = i * 64 + b; }
        if (mB) { int b = (int)__builtin_ctzll(mB); mB &= mB - 1;
                  vB = __shfl(dB, b, 64); iB = i * 64 + b; }
        if (mC) { int b = (int)__builtin_ctzll(mC); mC &= mC - 1;
                  vC = __shfl(dC, b, 64); iC = i * 64 + b; }
        if (mD) { int b = (int)__builtin_ctzll(mD); mD &= mD - 1;
                  vD = __shfl(dD, b, 64); iD = i * 64 + b; }
        // per-lane segment select of (v, vi)
        float v0 = (seg & 1) ? vB : vA;
        float v1 = (seg & 1) ? vD : vC;
        float v  = (seg & 2) ? v1 : v0;
        int  i0 = (seg & 1) ? iB : iA;
        int  i1 = (seg & 1) ? iD : iC;
        int  vi = (seg & 2) ? i1 : i0;
        // DPP within-segment shift-insert (pure VALU)
        float pd = dpp_shr1_f(Ld);
        int   pi = dpp_shr1_i(Li);
        if (segHead) pd = -INF;
        bool gt  = Ld > v;     // strict: equals keep rank (lower idx first)
        bool gtp = pd > v;
        Ld = gt ? (gtp ? pd : v) : Ld;
        Li = gt ? (gtp ? pi : vi) : Li;
      } while (mA | mB | mC | mD);
      tauA = __shfl(Ld, 15, 64);
      tauB = __shfl(Ld, 31, 64);
      tauC = __shfl(Ld, 47, 64);
      tauD = __shfl(Ld, 63, 64);
    }
  }

  float4 P = sp[Li];
  G[((size_t)bl * MQ + qbase + seg) * KNNK + (lane & 15)] =
      make_float4(P.x, P.y, P.z, 0.0f);

  // ---- fused coordinate moments (every lane holds exactly one sample) ----
  float mm[9];
  mm[0] = P.x; mm[1] = P.y; mm[2] = P.z;
  mm[3] = P.x * P.x; mm[4] = P.y * P.y; mm[5] = P.z * P.z;
  mm[6] = P.x * P.y; mm[7] = P.x * P.z; mm[8] = P.y * P.z;
#pragma unroll
  for (int j = 0; j < 9; ++j) {
#pragma unroll
    for (int o = 32; o >= 1; o >>= 1) mm[j] += __shfl_xor(mm[j], o, 64);
  }
  if (lane == 0) {
#pragma unroll
    for (int j = 0; j < 9; ++j) smom[wave][j] = mm[j];
  }
  __syncthreads();
  if (tid < 9) {
    float a = 0;
    for (int w = 0; w < 16; ++w) a += smom[w][tid];
    gmom[blockIdx.x * 9 + tid] = a;
  }

  // ---- fused stats1: last-arriving block computes BN1 scale/shift ----
  __threadfence();
  __syncthreads();
  if (tid == 0) lastBlk = (atomicAdd(cnt, 1) == 511);
  __syncthreads();
  if (lastBlk) {
    __threadfence();
    if (tid < 576) {
      int mom = tid >> 6, l = tid & 63;
      double s = 0;
      for (int b = l; b < 512; b += 64) s += (double)gmom[b * 9 + mom];
#pragma unroll
      for (int o = 32; o >= 1; o >>= 1) s += __shfl_down(s, o, 64);
      if (l == 0) mstat[mom] = s / (double)SAMP;
    }
    __syncthreads();
    if (tid < 64) {
      int c = tid;
      double Ex = mstat[0], Ey = mstat[1], Ez = mstat[2];
      double Exx = mstat[3], Eyy = mstat[4], Ezz = mstat[5];
      double Exy = mstat[6], Exz = mstat[7], Eyz = mstat[8];
      double wx = W1[c * 3 + 0], wy = W1[c * 3 + 1], wz = W1[c * 3 + 2], b = b1[c];
      double dot = wx * Ex + wy * Ey + wz * Ez;
      double mean = dot + b;
      double Ey2 = wx * wx * Exx + wy * wy * Eyy + wz * wz * Ezz
                 + 2.0 * (wx * wy * Exy + wx * wz * Exz + wy * wz * Eyz)
                 + 2.0 * b * dot + b * b;
      double var = Ey2 - mean * mean;
      double sc = (double)g1[c] / sqrt(var + 1e-5);
      s1out[c] = (float)sc;
      s1out[64 + c] = (float)((double)be1[c] - mean * sc);
    }
  }
}

// ---------------------------------------------------------------------------
// K3: z moments via split-bf16 MFMA (see R7 notes). 512 blocks x 256 threads.
// ---------------------------------------------------------------------------
__global__ __launch_bounds__(256) void zmom_kernel(const float4* __restrict__ G,
                                                   const float* __restrict__ W1,
                                                   const float* __restrict__ b1,
                                                   const float* __restrict__ s1,
                                                   float* __restrict__ zzp)
{
  __shared__ ushort zh[64][136];
  __shared__ ushort zl[64][136];

  const int tid = threadIdx.x;
  const int wave = tid >> 6;
  const int lane = tid & 63;
  const int p = lane;                  // sample pair 0..63
  const int c0base = wave * 16;        // staging channel block
  const int col = lane & 15;
  const int kr = lane >> 4;            // 0..3

  short8_b onesH;
#pragma unroll
  for (int j = 0; j < 8; ++j) onesH[j] = (short)0x3f80;   // bf16 1.0

  f32x4 acc0 = {0.f,0.f,0.f,0.f}, acc1 = {0.f,0.f,0.f,0.f};
  f32x4 acc2 = {0.f,0.f,0.f,0.f}, acc3 = {0.f,0.f,0.f,0.f};
  f32x4 accs = {0.f,0.f,0.f,0.f};

  const size_t sbase = (size_t)blockIdx.x * 1024;
  for (int t = 0; t < 8; ++t) {
    const size_t s0 = sbase + (size_t)t * 128;
    float4 g0 = G[s0 + 2 * p];
    float4 g1 = G[s0 + 2 * p + 1];
#pragma unroll
    for (int i = 0; i < 16; ++i) {
      const int c = c0base + i;
      const float w1x = W1[c * 3 + 0], w1y = W1[c * 3 + 1], w1z = W1[c * 3 + 2];
      const float bb1 = b1[c], sc1 = s1[c], sh1 = s1[64 + c];
      float y0 = fmaf(w1z, g0.z, fmaf(w1y, g0.y, fmaf(w1x, g0.x, bb1)));
      float y1 = fmaf(w1z, g1.z, fmaf(w1y, g1.y, fmaf(w1x, g1.x, bb1)));
      float z0 = fmaxf(fmaf(sc1, y0, sh1), 0.0f);
      float z1 = fmaxf(fmaf(sc1, y1, sh1), 0.0f);
      ushort h0 = f2bf(z0), h1 = f2bf(z1);
      float h0f = __uint_as_float((unsigned)h0 << 16);
      float h1f = __uint_as_float((unsigned)h1 << 16);
      ushort l0 = f2bf(z0 - h0f), l1 = f2bf(z1 - h1f);
      ((unsigned*)&zh[0][0])[c * 68 + p] = (unsigned)h0 | ((unsigned)h1 << 16);
      ((unsigned*)&zl[0][0])[c * 68 + p] = (unsigned)l0 | ((unsigned)l1 << 16);
    }
    __syncthreads();
#pragma unroll
    for (int kt = 0; kt < 4; ++kt) {
      const int soff = kt * 32 + kr * 8;
      short8_b Ah = *(const short8_b*)&zh[wave * 16 + col][soff];
      short8_b Al = *(const short8_b*)&zl[wave * 16 + col][soff];
      short8_b B0h = *(const short8_b*)&zh[ 0 + col][soff];
      short8_b B0l = *(const short8_b*)&zl[ 0 + col][soff];
      short8_b B1h = *(const short8_b*)&zh[16 + col][soff];
      short8_b B1l = *(const short8_b*)&zl[16 + col][soff];
      short8_b B2h = *(const short8_b*)&zh[32 + col][soff];
      short8_b B2l = *(const short8_b*)&zl[32 + col][soff];
      short8_b B3h = *(const short8_b*)&zh[48 + col][soff];
      short8_b B3l = *(const short8_b*)&zl[48 + col][soff];
      acc0 = __builtin_amdgcn_mfma_f32_16x16x32_bf16(Ah, B0h, acc0, 0, 0, 0);
      acc0 = __builtin_amdgcn_mfma_f32_16x16x32_bf16(Ah, B0l, acc0, 0, 0, 0);
      acc0 = __builtin_amdgcn_mfma_f32_16x16x32_bf16(Al, B0h, acc0, 0, 0, 0);
      acc1 = __builtin_amdgcn_mfma_f32_16x16x32_bf16(Ah, B1h, acc1, 0, 0, 0);
      acc1 = __builtin_amdgcn_mfma_f32_16x16x32_bf16(Ah, B1l, acc1, 0, 0, 0);
      acc1 = __builtin_amdgcn_mfma_f32_16x16x32_bf16(Al, B1h, acc1, 0, 0, 0);
      acc2 = __builtin_amdgcn_mfma_f32_16x16x32_bf16(Ah, B2h, acc2, 0, 0, 0);
      acc2 = __builtin_amdgcn_mfma_f32_16x16x32_bf16(Ah, B2l, acc2, 0, 0, 0);
      acc2 = __builtin_amdgcn_mfma_f32_16x16x32_bf16(Al, B2h, acc2, 0, 0, 0);
      acc3 = __builtin_amdgcn_mfma_f32_16x16x32_bf16(Ah, B3h, acc3, 0, 0, 0);
      acc3 = __builtin_amdgcn_mfma_f32_16x16x32_bf16(Ah, B3l, acc3, 0, 0, 0);
      acc3 = __builtin_amdgcn_mfma_f32_16x16x32_bf16(Al, B3h, acc3, 0, 0, 0);
      accs = __builtin_amdgcn_mfma_f32_16x16x32_bf16(Ah, onesH, accs, 0, 0, 0);
      accs = __builtin_amdgcn_mfma_f32_16x16x32_bf16(Al, onesH, accs, 0, 0, 0);
    }
    __syncthreads();
  }

  float* outp = zzp + (size_t)blockIdx.x * ZZW;
#pragma unroll
  for (int i = 0; i < 4; ++i) {
    const int row = wave * 16 + kr * 4 + i;
    outp[row * 64 +  0 + col] = acc0[i];
    outp[row * 64 + 16 + col] = acc1[i];
    outp[row * 64 + 32 + col] = acc2[i];
    outp[row * 64 + 48 + col] = acc3[i];
  }
  if (col == 0) {
#pragma unroll
    for (int i = 0; i < 4; ++i)
      outp[4096 + wave * 16 + kr * 4 + i] = accs[i];
  }
}

// ---------------------------------------------------------------------------
// K4: reduce zz partials over blocks -> double. 130 blocks x 256 threads:
// block handles 32 columns; thread (part, jl) sums a 64-partial chunk of
// column jl; LDS reduce over the 8 parts (fixed order -> deterministic).
// ---------------------------------------------------------------------------
__global__ __launch_bounds__(256) void zzred_kernel(const float* __restrict__ zzp,
                                                    double* __restrict__ zzs)
{
  __shared__ double pr[8][33];
  const int t = threadIdx.x;
  const int jl = t & 31, part = t >> 5;
  const int j = blockIdx.x * 32 + jl;
  double s = 0;
  if (j < ZZW) {
    const int b0 = part * 64;
    for (int b = b0; b < b0 + 64; ++b) s += (double)zzp[(size_t)b * ZZW + j];
  }
  pr[part][jl] = s;
  __syncthreads();
  if (t < 32) {
    const int jj = blockIdx.x * 32 + t;
    if (jj < ZZW) {
      double a = 0;
#pragma unroll
      for (int p = 0; p < 8; ++p) a += pr[p][t];
      zzs[jj] = a;
    }
  }
}

// ---------------------------------------------------------------------------
// K5: stats2 — BN2 stats via quadratic form + W2 bf16 hi/lo split.
// ---------------------------------------------------------------------------
__global__ void stats2_kernel(const double* __restrict__ zzs,
                              const float* __restrict__ W2, const float* __restrict__ b2,
                              const float* __restrict__ g2, const float* __restrict__ be2,
                              float* __restrict__ s2out,
                              ushort* __restrict__ w2h, ushort* __restrict__ w2l)
{
  int d = blockIdx.x;
  int c = threadIdx.x;  // 0..63

  {
    int idx = d * 64 + c;
    float w = W2[idx];
    ushort h = f2bf(w);
    float wh = __uint_as_float((unsigned)h << 16);
    ushort l = f2bf(w - wh);
    w2h[idx] = h;
    w2l[idx] = l;
  }

  double w_c = (double)W2[(size_t)d * 64 + c];
  double h = 0;
  for (int c2 = 0; c2 < 64; ++c2)
    h += (double)W2[(size_t)d * 64 + c2] * zzs[c * 64 + c2];
  double quad = w_c * h;
  double dz = w_c * zzs[4096 + c];
#pragma unroll
  for (int o = 32; o >= 1; o >>= 1) {
    quad += __shfl_down(quad, o, 64);
    dz += __shfl_down(dz, o, 64);
  }
  if (c == 0) {
    double S = (double)SAMP, b = (double)b2[d];
    double mean = dz / S + b;
    double Ey2 = (quad + 2.0 * b * dz) / S + b * b;
    double var = Ey2 - mean * mean;
    double sc = (double)g2[d] / sqrt(var + 1e-5);
    s2out[d] = (float)sc;
    s2out[128 + d] = (float)((double)be2[d] - mean * sc);
  }
}

// ---------------------------------------------------------------------------
// K6: output pass — split-bf16 MFMA GEMM; nontemporal stores for the 256 MB
// streaming write (no reuse of out -> bypass L2). 4096 blocks.
// ---------------------------------------------------------------------------
__global__ __launch_bounds__(256) void out_kernel(const float4* __restrict__ G,
                                                  const float* __restrict__ W1,
                                                  const float* __restrict__ b1,
                                                  const float* __restrict__ s1,
                                                  const ushort* __restrict__ w2h,
                                                  const ushort* __restrict__ w2l,
                                                  const float* __restrict__ b2,
                                                  const float* __restrict__ s2,
                                                  float* __restrict__ out)
{
  __shared__ ushort zh[128][72];   // bf16 hi, row pitch 144B (16B-aligned)
  __shared__ ushort zl[128][72];   // bf16 lo

  const int tid = threadIdx.x;
  const int wave = tid >> 6;
  const int lane = tid & 63;
  const size_t sbase = (size_t)blockIdx.x * 128;

  {
    const int zc = tid & 63;
    const float w1x = W1[zc * 3 + 0], w1y = W1[zc * 3 + 1], w1z = W1[zc * 3 + 2];
    const float bb1 = b1[zc], sc1 = s1[zc], sh1 = s1[64 + zc];
#pragma unroll 4
    for (int k = 0; k < 32; ++k) {
      int s = (tid >> 6) + k * 4;
      float4 g = G[sbase + s];
      float y = fmaf(w1z, g.z, fmaf(w1y, g.y, fmaf(w1x, g.x, bb1)));
      float z = fmaxf(fmaf(sc1, y, sh1), 0.0f);
      ushort h = f2bf(z);
      float zhf = __uint_as_float((unsigned)h << 16);
      zh[s][zc] = h;
      zl[s][zc] = f2bf(z - zhf);
    }
  }

  const int col = lane & 15;
  const int krow = (lane >> 4) * 8;
  const int d0 = wave * 32 + col;
  const int d1 = d0 + 16;
  short8_b Bh0[2], Bl0[2], Bh1[2], Bl1[2];
#pragma unroll
  for (int kk = 0; kk < 2; ++kk) {
    int c0 = kk * 32 + krow;
    Bh0[kk] = *(const short8_b*)(w2h + d0 * 64 + c0);
    Bl0[kk] = *(const short8_b*)(w2l + d0 * 64 + c0);
    Bh1[kk] = *(const short8_b*)(w2h + d1 * 64 + c0);
    Bl1[kk] = *(const short8_b*)(w2l + d1 * 64 + c0);
  }
  const float bv0 = b2[d0], scv0 = s2[d0], shv0 = s2[128 + d0];
  const float bv1 = b2[d1], scv1 = s2[d1], shv1 = s2[128 + d1];

  __syncthreads();

  for (int m = 0; m < 8; ++m) {
    const int row = m * 16 + col;
    short8_b Ah[2], Al[2];
#pragma unroll
    for (int kk = 0; kk < 2; ++kk) {
      int c0 = kk * 32 + krow;
      Ah[kk] = *(const short8_b*)&zh[row][c0];
      Al[kk] = *(const short8_b*)&zl[row][c0];
    }
    f32x4 acc0 = {0.f, 0.f, 0.f, 0.f};
    f32x4 acc1 = {0.f, 0.f, 0.f, 0.f};
#pragma unroll
    for (int kk = 0; kk < 2; ++kk) {
      acc0 = __builtin_amdgcn_mfma_f32_16x16x32_bf16(Ah[kk], Bh0[kk], acc0, 0, 0, 0);
      acc0 = __builtin_amdgcn_mfma_f32_16x16x32_bf16(Ah[kk], Bl0[kk], acc0, 0, 0, 0);
      acc0 = __builtin_amdgcn_mfma_f32_16x16x32_bf16(Al[kk], Bh0[kk], acc0, 0, 0, 0);
      acc1 = __builtin_amdgcn_mfma_f32_16x16x32_bf16(Ah[kk], Bh1[kk], acc1, 0, 0, 0);
      acc1 = __builtin_amdgcn_mfma_f32_16x16x32_bf16(Ah[kk], Bl1[kk], acc1, 0, 0, 0);
      acc1 = __builtin_amdgcn_mfma_f32_16x16x32_bf16(Al[kk], Bh1[kk], acc1, 0, 0, 0);
    }
    const size_t srow = sbase + m * 16 + (lane >> 4) * 4;
#pragma unroll
    for (int i = 0; i < 4; ++i) {
      float o0 = fmaxf(fmaf(scv0, acc0[i] + bv0, shv0), 0.0f);
      float o1 = fmaxf(fmaf(scv1, acc1[i] + bv1, shv1), 0.0f);
      __builtin_nontemporal_store(o0, &out[(srow + i) * 128 + d0]);
      __builtin_nontemporal_store(o1, &out[(srow + i) * 128 + d1]);
    }
  }
}

// ---------------------------------------------------------------------------
extern "C" void kernel_launch(void* const* d_in, const int* in_sizes, int n_in,
                              void* d_out, int out_size, void* d_ws, size_t ws_size,
                              hipStream_t stream)
{
  const float* points  = (const float*)d_in[0];
  const float* queries = (const float*)d_in[1];
  const float* W1      = (const float*)d_in[2];
  const float* b1      = (const float*)d_in[3];
  const float* gamma1  = (const float*)d_in[4];
  const float* beta1   = (const float*)d_in[5];
  const float* W2      = (const float*)d_in[6];
  const float* b2      = (const float*)d_in[7];
  const float* gamma2  = (const float*)d_in[8];
  const float* beta2   = (const float*)d_in[9];

  char* ws = (char*)d_ws;
  float4* G    = (float4*)(ws + OFF_G);
  float*  gmom = (float*)(ws + OFF_GMOM);
  float*  s1   = (float*)(ws + OFF_S1);
  float*  zzp  = (float*)(ws + OFF_ZZP);
  double* zzs  = (double*)(ws + OFF_ZZS);
  float*  s2   = (float*)(ws + OFF_S2);
  ushort* w2h  = (ushort*)(ws + OFF_W2H);
  ushort* w2l  = (ushort*)(ws + OFF_W2L);
  int*    cnt  = (int*)(ws + OFF_CNT);
  float*  out  = (float*)d_out;

  hipMemsetAsync(cnt, 0, sizeof(int), stream);
  knn_kernel<<<512, 1024, 0, stream>>>(points, queries, G, gmom,
                                       W1, b1, gamma1, beta1, s1, cnt);
  zmom_kernel<<<NBLK_ZZ, 256, 0, stream>>>(G, W1, b1, s1, zzp);
  zzred_kernel<<<130, 256, 0, stream>>>(zzp, zzs);
  stats2_kernel<<<128, 64, 0, stream>>>(zzs, W2, b2, gamma2, beta2, s2, w2h, w2l);
  out_kernel<<<4096, 256, 0, stream>>>(G, W1, b1, s1, w2h, w2l, b2, s2, out);
}

// Round 15
// 218.283 us; speedup vs baseline: 1.4163x; 1.4163x over previous
//
#include <hip/hip_runtime.h>
#include <cmath>

// Problem constants
constexpr int BB = 4, LL = 8, NPTS = 4096, MQ = 1024, KNNK = 16;
constexpr int C1 = 64, C2 = 128;
constexpr int NSLICE = BB * LL;                       // 32
constexpr long long SAMP = (long long)NSLICE * MQ * KNNK;  // 524288 samples
constexpr int NBLK_ZZ = 512;
constexpr int ZZW = C1 * C1 + C1;                     // 4160 (full 64x64 + sum_z)

// Workspace layout (bytes)
constexpr size_t OFF_G    = 0;                                   // float4[SAMP] = 8 MB
constexpr size_t OFF_GMOM = (size_t)8 * 1024 * 1024;             // float[512*9]
constexpr size_t OFF_S1   = OFF_GMOM + 20480;                    // float[128]: scale1,shift1
constexpr size_t OFF_ZZP  = OFF_S1 + 1024;                       // float[NBLK_ZZ*ZZW]
constexpr size_t OFF_ZZS  = OFF_ZZP + (size_t)NBLK_ZZ * ZZW * 4; // double[ZZW]
constexpr size_t OFF_S2   = OFF_ZZS + (size_t)ZZW * 8;           // float[256]: scale2,shift2
// W2 hi/lo bf16 splits: reuse the zzp region (dead after zzred, before stats2)
constexpr size_t OFF_W2H  = OFF_ZZP;                             // ushort[8192]
constexpr size_t OFF_W2L  = OFF_ZZP + 16384;                     // ushort[8192]

typedef __attribute__((ext_vector_type(8))) short short8_b;   // 8 bf16 (4 VGPRs)
typedef __attribute__((ext_vector_type(4))) float f32x4;

__device__ inline ushort f2bf(float f) {        // RNE float -> bf16 bits
  unsigned u = __float_as_uint(f);
  return (ushort)((u + 0x7fffu + ((u >> 16) & 1u)) >> 16);
}

// DPP row_shr:1 within 16-lane rows (segments ARE rows). Row-head lanes keep
// the literal-0 'old' (bound_ctrl=false) and are overridden by the segHead fix.
__device__ inline float dpp_shr1_f(float x) {
  return __uint_as_float((unsigned)__builtin_amdgcn_update_dpp(
      0, (int)__float_as_uint(x), 0x111, 0xF, 0xF, false));
}
__device__ inline int dpp_shr1_i(int x) {
  return __builtin_amdgcn_update_dpp(0, x, 0x111, 0xF, 0xF, false);
}

// ---------------------------------------------------------------------------
// K1: per-slice KNN + gather + fused coordinate moments (R11 best-measured
// form: bitonic seed, branchy pops with __shfl broadcasts, DPP shift-insert;
// NO stats1 tail — R14 showed grafting it perturbs the hot loop's codegen).
// 512 blocks x 1024 threads.
// ---------------------------------------------------------------------------
__global__ __launch_bounds__(1024, 8) void knn_kernel(const float* __restrict__ pts,
                                                      const float* __restrict__ qrs,
                                                      float4* __restrict__ G,
                                                      float* __restrict__ gmom)
{
#pragma clang fp contract(off)
  __shared__ float4 sp[NPTS];   // (x,y,z,p2) = 64 KB
  __shared__ float smom[16][9];
  const int tid = threadIdx.x;
  const int bl = blockIdx.x >> 4;    // slice (32)
  const int qt = blockIdx.x & 15;    // 16 query tiles of 64
  const int wave = tid >> 6;
  const int lane = tid & 63;
  const float INF = 3.402823466e38f;

  const float* pb = pts + (size_t)bl * NPTS * 3;
  for (int p = tid; p < NPTS; p += 1024) {
    float x = pb[p * 3 + 0], y = pb[p * 3 + 1], z = pb[p * 3 + 2];
    float pp = (x * x + y * y) + z * z;       // plain rounding
    sp[p] = make_float4(x, y, z, pp);
  }
  __syncthreads();

  const int qbase = qt * 64 + wave * 4;
  const float* qp = qrs + ((size_t)bl * MQ + qbase) * 3;
  const float qxA = qp[0], qyA = qp[1], qzA = qp[2];
  const float qxB = qp[3], qyB = qp[4], qzB = qp[5];
  const float qxC = qp[6], qyC = qp[7], qzC = qp[8];
  const float qxD = qp[9], qyD = qp[10], qzD = qp[11];
  const float q2A = (qxA * qxA + qyA * qyA) + qzA * qzA;   // plain rounding
  const float q2B = (qxB * qxB + qyB * qyB) + qzB * qzB;
  const float q2C = (qxC * qxC + qyC * qyC) + qzC * qzC;
  const float q2D = (qxD * qxD + qyD * qyD) + qzD * qzD;

  const int seg = lane >> 4;
  const bool segHead = (lane & 15) == 0;

  float Ld; int Li;
  float tauA, tauB, tauC, tauD;

  // ---- seed (i = 0): bitonic sort of 64 (d, lane) keys per query ----
  {
    float4 P = sp[lane];
    float pqA = fmaf(P.z, qzA, fmaf(P.y, qyA, P.x * qxA));
    float pqB = fmaf(P.z, qzB, fmaf(P.y, qyB, P.x * qxB));
    float pqC = fmaf(P.z, qzC, fmaf(P.y, qyC, P.x * qxC));
    float pqD = fmaf(P.z, qzD, fmaf(P.y, qyD, P.x * qxD));
    float dA = fmaf(-2.0f, pqA, q2A + P.w);
    float dB = fmaf(-2.0f, pqB, q2B + P.w);
    float dC = fmaf(-2.0f, pqC, q2C + P.w);
    float dD = fmaf(-2.0f, pqD, q2D + P.w);

    unsigned uA = __float_as_uint(dA); uA = (uA & 0x80000000u) ? ~uA : (uA | 0x80000000u);
    unsigned uB = __float_as_uint(dB); uB = (uB & 0x80000000u) ? ~uB : (uB | 0x80000000u);
    unsigned uC = __float_as_uint(dC); uC = (uC & 0x80000000u) ? ~uC : (uC | 0x80000000u);
    unsigned uD = __float_as_uint(dD); uD = (uD & 0x80000000u) ? ~uD : (uD | 0x80000000u);
    unsigned long long kA = ((unsigned long long)uA << 6) | (unsigned)lane;
    unsigned long long kB = ((unsigned long long)uB << 6) | (unsigned)lane;
    unsigned long long kC = ((unsigned long long)uC << 6) | (unsigned)lane;
    unsigned long long kD = ((unsigned long long)uD << 6) | (unsigned)lane;

#pragma unroll
    for (int k = 2; k <= 64; k <<= 1) {
#pragma unroll
      for (int j = k >> 1; j >= 1; j >>= 1) {
        const bool selMin = ((lane & j) == 0) == ((lane & k) == 0);
        unsigned long long pA = __shfl_xor(kA, j, 64);
        unsigned long long pB = __shfl_xor(kB, j, 64);
        unsigned long long pC = __shfl_xor(kC, j, 64);
        unsigned long long pD = __shfl_xor(kD, j, 64);
        kA = ((kA < pA) == selMin) ? kA : pA;
        kB = ((kB < pB) == selMin) ? kB : pB;
        kC = ((kC < pC) == selMin) ? kC : pC;
        kD = ((kD < pD) == selMin) ? kD : pD;
      }
    }

    const int src = lane & 15;
    unsigned long long rA = __shfl(kA, src, 64);
    unsigned long long rB = __shfl(kB, src, 64);
    unsigned long long rC = __shfl(kC, src, 64);
    unsigned long long rD = __shfl(kD, src, 64);
    unsigned long long r0 = (seg & 1) ? rB : rA;
    unsigned long long r1 = (seg & 1) ? rD : rC;
    unsigned long long rr = (seg & 2) ? r1 : r0;
    unsigned um = (unsigned)(rr >> 6);
    um = (um & 0x80000000u) ? (um & 0x7fffffffu) : ~um;    // inverse map
    Ld = __uint_as_float(um);
    Li = (int)(rr & 63u);
    tauA = __shfl(Ld, 15, 64);
    tauB = __shfl(Ld, 31, 64);
    tauC = __shfl(Ld, 47, 64);
    tauD = __shfl(Ld, 63, 64);
  }

  // ---- main scan: i = 1..63 ----
  for (int i = 1; i < 64; ++i) {
    float4 P = sp[i * 64 + lane];
    float pqA = fmaf(P.z, qzA, fmaf(P.y, qyA, P.x * qxA));
    float pqB = fmaf(P.z, qzB, fmaf(P.y, qyB, P.x * qxB));
    float pqC = fmaf(P.z, qzC, fmaf(P.y, qyC, P.x * qxC));
    float pqD = fmaf(P.z, qzD, fmaf(P.y, qyD, P.x * qxD));
    float dA = fmaf(-2.0f, pqA, q2A + P.w);
    float dB = fmaf(-2.0f, pqB, q2B + P.w);
    float dC = fmaf(-2.0f, pqC, q2C + P.w);
    float dD = fmaf(-2.0f, pqD, q2D + P.w);

    unsigned long long mA = __ballot(dA < tauA);
    unsigned long long mB = __ballot(dB < tauB);
    unsigned long long mC = __ballot(dC < tauC);
    unsigned long long mD = __ballot(dD < tauD);

    if (mA | mB | mC | mD) {
      do {
        float vA = INF, vB = INF, vC = INF, vD = INF;
        int iA = 0, iB = 0, iC = 0, iD = 0;
        if (mA) { int b = (int)__builtin_ctzll(mA); mA &= mA - 1;
                  vA = __shfl(dA, b, 64); iA = i * 64 + b; }
        if (mB) { int b = (int)__builtin_ctzll(mB); mB &= mB - 1;
                  vB = __shfl(dB, b, 64); iB = i * 64 + b; }
        if (mC) { int b = (int)__builtin_ctzll(mC); mC &= mC - 1;
                  vC = __shfl(dC, b, 64); iC = i * 64 + b; }
        if (mD) { int b = (int)__builtin_ctzll(mD); mD &= mD - 1;
                  vD = __shfl(dD, b, 64); iD = i * 64 + b; }
        // per-lane segment select of (v, vi)
        float v0 = (seg & 1) ? vB : vA;
        float v1 = (seg & 1) ? vD : vC;
        float v  = (seg & 2) ? v1 : v0;
        int  i0 = (seg & 1) ? iB : iA;
        int  i1 = (seg & 1) ? iD : iC;
        int  vi = (seg & 2) ? i1 : i0;
        // DPP within-segment shift-insert (pure VALU)
        float pd = dpp_shr1_f(Ld);
        int   pi = dpp_shr1_i(Li);
        if (segHead) pd = -INF;
        bool gt  = Ld > v;     // strict: equals keep rank (lower idx first)
        bool gtp = pd > v;
        Ld = gt ? (gtp ? pd : v) : Ld;
        Li = gt ? (gtp ? pi : vi) : Li;
      } while (mA | mB | mC | mD);
      tauA = __shfl(Ld, 15, 64);
      tauB = __shfl(Ld, 31, 64);
      tauC = __shfl(Ld, 47, 64);
      tauD = __shfl(Ld, 63, 64);
    }
  }

  float4 P = sp[Li];
  G[((size_t)bl * MQ + qbase + seg) * KNNK + (lane & 15)] =
      make_float4(P.x, P.y, P.z, 0.0f);

  // ---- fused coordinate moments (every lane holds exactly one sample) ----
  float mm[9];
  mm[0] = P.x; mm[1] = P.y; mm[2] = P.z;
  mm[3] = P.x * P.x; mm[4] = P.y * P.y; mm[5] = P.z * P.z;
  mm[6] = P.x * P.y; mm[7] = P.x * P.z; mm[8] = P.y * P.z;
#pragma unroll
  for (int j = 0; j < 9; ++j) {
#pragma unroll
    for (int o = 32; o >= 1; o >>= 1) mm[j] += __shfl_xor(mm[j], o, 64);
  }
  if (lane == 0) {
#pragma unroll
    for (int j = 0; j < 9; ++j) smom[wave][j] = mm[j];
  }
  __syncthreads();
  if (tid < 9) {
    float a = 0;
    for (int w = 0; w < 16; ++w) a += smom[w][tid];
    gmom[blockIdx.x * 9 + tid] = a;
  }
}

// ---------------------------------------------------------------------------
// K2: stats1 — analytic BN1 stats from coord moments (1 block, 576 threads)
// ---------------------------------------------------------------------------
__global__ void stats1_kernel(const float* __restrict__ gmom,
                              const float* __restrict__ W1, const float* __restrict__ b1,
                              const float* __restrict__ g1, const float* __restrict__ be1,
                              float* __restrict__ s1out)
{
  __shared__ double m[9];
  const int t = threadIdx.x;
  const int mom = t >> 6, lane = t & 63;
  if (mom < 9) {
    double s = 0;
    for (int b = lane; b < 512; b += 64) s += (double)gmom[b * 9 + mom];
#pragma unroll
    for (int o = 32; o >= 1; o >>= 1) s += __shfl_down(s, o, 64);
    if (lane == 0) m[mom] = s / (double)SAMP;
  }
  __syncthreads();
  if (t < 64) {
    int c = t;
    double Ex = m[0], Ey = m[1], Ez = m[2];
    double Exx = m[3], Eyy = m[4], Ezz = m[5], Exy = m[6], Exz = m[7], Eyz = m[8];
    double wx = W1[c * 3 + 0], wy = W1[c * 3 + 1], wz = W1[c * 3 + 2], b = b1[c];
    double dot = wx * Ex + wy * Ey + wz * Ez;
    double mean = dot + b;
    double Ey2 = wx * wx * Exx + wy * wy * Eyy + wz * wz * Ezz
               + 2.0 * (wx * wy * Exy + wx * wz * Exz + wy * wz * Eyz)
               + 2.0 * b * dot + b * b;
    double var = Ey2 - mean * mean;
    double sc = (double)g1[c] / sqrt(var + 1e-5);
    s1out[c] = (float)sc;
    s1out[64 + c] = (float)((double)be1[c] - mean * sc);
  }
}

// ---------------------------------------------------------------------------
// K3: z moments via split-bf16 MFMA (see R7 notes). 512 blocks x 256 threads.
// ---------------------------------------------------------------------------
__global__ __launch_bounds__(256) void zmom_kernel(const float4* __restrict__ G,
                                                   const float* __restrict__ W1,
                                                   const float* __restrict__ b1,
                                                   const float* __restrict__ s1,
                                                   float* __restrict__ zzp)
{
  __shared__ ushort zh[64][136];
  __shared__ ushort zl[64][136];

  const int tid = threadIdx.x;
  const int wave = tid >> 6;
  const int lane = tid & 63;
  const int p = lane;                  // sample pair 0..63
  const int c0base = wave * 16;        // staging channel block
  const int col = lane & 15;
  const int kr = lane >> 4;            // 0..3

  short8_b onesH;
#pragma unroll
  for (int j = 0; j < 8; ++j) onesH[j] = (short)0x3f80;   // bf16 1.0

  f32x4 acc0 = {0.f,0.f,0.f,0.f}, acc1 = {0.f,0.f,0.f,0.f};
  f32x4 acc2 = {0.f,0.f,0.f,0.f}, acc3 = {0.f,0.f,0.f,0.f};
  f32x4 accs = {0.f,0.f,0.f,0.f};

  const size_t sbase = (size_t)blockIdx.x * 1024;
  for (int t = 0; t < 8; ++t) {
    const size_t s0 = sbase + (size_t)t * 128;
    float4 g0 = G[s0 + 2 * p];
    float4 g1 = G[s0 + 2 * p + 1];
#pragma unroll
    for (int i = 0; i < 16; ++i) {
      const int c = c0base + i;
      const float w1x = W1[c * 3 + 0], w1y = W1[c * 3 + 1], w1z = W1[c * 3 + 2];
      const float bb1 = b1[c], sc1 = s1[c], sh1 = s1[64 + c];
      float y0 = fmaf(w1z, g0.z, fmaf(w1y, g0.y, fmaf(w1x, g0.x, bb1)));
      float y1 = fmaf(w1z, g1.z, fmaf(w1y, g1.y, fmaf(w1x, g1.x, bb1)));
      float z0 = fmaxf(fmaf(sc1, y0, sh1), 0.0f);
      float z1 = fmaxf(fmaf(sc1, y1, sh1), 0.0f);
      ushort h0 = f2bf(z0), h1 = f2bf(z1);
      float h0f = __uint_as_float((unsigned)h0 << 16);
      float h1f = __uint_as_float((unsigned)h1 << 16);
      ushort l0 = f2bf(z0 - h0f), l1 = f2bf(z1 - h1f);
      ((unsigned*)&zh[0][0])[c * 68 + p] = (unsigned)h0 | ((unsigned)h1 << 16);
      ((unsigned*)&zl[0][0])[c * 68 + p] = (unsigned)l0 | ((unsigned)l1 << 16);
    }
    __syncthreads();
#pragma unroll
    for (int kt = 0; kt < 4; ++kt) {
      const int soff = kt * 32 + kr * 8;
      short8_b Ah = *(const short8_b*)&zh[wave * 16 + col][soff];
      short8_b Al = *(const short8_b*)&zl[wave * 16 + col][soff];
      short8_b B0h = *(const short8_b*)&zh[ 0 + col][soff];
      short8_b B0l = *(const short8_b*)&zl[ 0 + col][soff];
      short8_b B1h = *(const short8_b*)&zh[16 + col][soff];
      short8_b B1l = *(const short8_b*)&zl[16 + col][soff];
      short8_b B2h = *(const short8_b*)&zh[32 + col][soff];
      short8_b B2l = *(const short8_b*)&zl[32 + col][soff];
      short8_b B3h = *(const short8_b*)&zh[48 + col][soff];
      short8_b B3l = *(const short8_b*)&zl[48 + col][soff];
      acc0 = __builtin_amdgcn_mfma_f32_16x16x32_bf16(Ah, B0h, acc0, 0, 0, 0);
      acc0 = __builtin_amdgcn_mfma_f32_16x16x32_bf16(Ah, B0l, acc0, 0, 0, 0);
      acc0 = __builtin_amdgcn_mfma_f32_16x16x32_bf16(Al, B0h, acc0, 0, 0, 0);
      acc1 = __builtin_amdgcn_mfma_f32_16x16x32_bf16(Ah, B1h, acc1, 0, 0, 0);
      acc1 = __builtin_amdgcn_mfma_f32_16x16x32_bf16(Ah, B1l, acc1, 0, 0, 0);
      acc1 = __builtin_amdgcn_mfma_f32_16x16x32_bf16(Al, B1h, acc1, 0, 0, 0);
      acc2 = __builtin_amdgcn_mfma_f32_16x16x32_bf16(Ah, B2h, acc2, 0, 0, 0);
      acc2 = __builtin_amdgcn_mfma_f32_16x16x32_bf16(Ah, B2l, acc2, 0, 0, 0);
      acc2 = __builtin_amdgcn_mfma_f32_16x16x32_bf16(Al, B2h, acc2, 0, 0, 0);
      acc3 = __builtin_amdgcn_mfma_f32_16x16x32_bf16(Ah, B3h, acc3, 0, 0, 0);
      acc3 = __builtin_amdgcn_mfma_f32_16x16x32_bf16(Ah, B3l, acc3, 0, 0, 0);
      acc3 = __builtin_amdgcn_mfma_f32_16x16x32_bf16(Al, B3h, acc3, 0, 0, 0);
      accs = __builtin_amdgcn_mfma_f32_16x16x32_bf16(Ah, onesH, accs, 0, 0, 0);
      accs = __builtin_amdgcn_mfma_f32_16x16x32_bf16(Al, onesH, accs, 0, 0, 0);
    }
    __syncthreads();
  }

  float* outp = zzp + (size_t)blockIdx.x * ZZW;
#pragma unroll
  for (int i = 0; i < 4; ++i) {
    const int row = wave * 16 + kr * 4 + i;
    outp[row * 64 +  0 + col] = acc0[i];
    outp[row * 64 + 16 + col] = acc1[i];
    outp[row * 64 + 32 + col] = acc2[i];
    outp[row * 64 + 48 + col] = acc3[i];
  }
  if (col == 0) {
#pragma unroll
    for (int i = 0; i < 4; ++i)
      outp[4096 + wave * 16 + kr * 4 + i] = accs[i];
  }
}

// ---------------------------------------------------------------------------
// K4: reduce zz partials over blocks -> double. 130 blocks x 256 threads:
// block handles 32 columns; thread (part, jl) sums a 64-partial chunk of
// column jl; LDS reduce over the 8 parts (fixed order -> deterministic).
// ---------------------------------------------------------------------------
__global__ __launch_bounds__(256) void zzred_kernel(const float* __restrict__ zzp,
                                                    double* __restrict__ zzs)
{
  __shared__ double pr[8][33];
  const int t = threadIdx.x;
  const int jl = t & 31, part = t >> 5;
  const int j = blockIdx.x * 32 + jl;
  double s = 0;
  if (j < ZZW) {
    const int b0 = part * 64;
    for (int b = b0; b < b0 + 64; ++b) s += (double)zzp[(size_t)b * ZZW + j];
  }
  pr[part][jl] = s;
  __syncthreads();
  if (t < 32) {
    const int jj = blockIdx.x * 32 + t;
    if (jj < ZZW) {
      double a = 0;
#pragma unroll
      for (int p = 0; p < 8; ++p) a += pr[p][t];
      zzs[jj] = a;
    }
  }
}

// ---------------------------------------------------------------------------
// K5: stats2 — BN2 stats via quadratic form + W2 bf16 hi/lo split.
// ---------------------------------------------------------------------------
__global__ void stats2_kernel(const double* __restrict__ zzs,
                              const float* __restrict__ W2, const float* __restrict__ b2,
                              const float* __restrict__ g2, const float* __restrict__ be2,
                              float* __restrict__ s2out,
                              ushort* __restrict__ w2h, ushort* __restrict__ w2l)
{
  int d = blockIdx.x;
  int c = threadIdx.x;  // 0..63

  {
    int idx = d * 64 + c;
    float w = W2[idx];
    ushort h = f2bf(w);
    float wh = __uint_as_float((unsigned)h << 16);
    ushort l = f2bf(w - wh);
    w2h[idx] = h;
    w2l[idx] = l;
  }

  double w_c = (double)W2[(size_t)d * 64 + c];
  double h = 0;
  for (int c2 = 0; c2 < 64; ++c2)
    h += (double)W2[(size_t)d * 64 + c2] * zzs[c * 64 + c2];
  double quad = w_c * h;
  double dz = w_c * zzs[4096 + c];
#pragma unroll
  for (int o = 32; o >= 1; o >>= 1) {
    quad += __shfl_down(quad, o, 64);
    dz += __shfl_down(dz, o, 64);
  }
  if (c == 0) {
    double S = (double)SAMP, b = (double)b2[d];
    double mean = dz / S + b;
    double Ey2 = (quad + 2.0 * b * dz) / S + b * b;
    double var = Ey2 - mean * mean;
    double sc = (double)g2[d] / sqrt(var + 1e-5);
    s2out[d] = (float)sc;
    s2out[128 + d] = (float)((double)be2[d] - mean * sc);
  }
}

// ---------------------------------------------------------------------------
// K6: output pass — split-bf16 MFMA GEMM; nontemporal stores for the 256 MB
// streaming write (no reuse of out -> bypass L2). 4096 blocks.
// ---------------------------------------------------------------------------
__global__ __launch_bounds__(256) void out_kernel(const float4* __restrict__ G,
                                                  const float* __restrict__ W1,
                                                  const float* __restrict__ b1,
                                                  const float* __restrict__ s1,
                                                  const ushort* __restrict__ w2h,
                                                  const ushort* __restrict__ w2l,
                                                  const float* __restrict__ b2,
                                                  const float* __restrict__ s2,
                                                  float* __restrict__ out)
{
  __shared__ ushort zh[128][72];   // bf16 hi, row pitch 144B (16B-aligned)
  __shared__ ushort zl[128][72];   // bf16 lo

  const int tid = threadIdx.x;
  const int wave = tid >> 6;
  const int lane = tid & 63;
  const size_t sbase = (size_t)blockIdx.x * 128;

  {
    const int zc = tid & 63;
    const float w1x = W1[zc * 3 + 0], w1y = W1[zc * 3 + 1], w1z = W1[zc * 3 + 2];
    const float bb1 = b1[zc], sc1 = s1[zc], sh1 = s1[64 + zc];
#pragma unroll 4
    for (int k = 0; k < 32; ++k) {
      int s = (tid >> 6) + k * 4;
      float4 g = G[sbase + s];
      float y = fmaf(w1z, g.z, fmaf(w1y, g.y, fmaf(w1x, g.x, bb1)));
      float z = fmaxf(fmaf(sc1, y, sh1), 0.0f);
      ushort h = f2bf(z);
      float zhf = __uint_as_float((unsigned)h << 16);
      zh[s][zc] = h;
      zl[s][zc] = f2bf(z - zhf);
    }
  }

  const int col = lane & 15;
  const int krow = (lane >> 4) * 8;
  const int d0 = wave * 32 + col;
  const int d1 = d0 + 16;
  short8_b Bh0[2], Bl0[2], Bh1[2], Bl1[2];
#pragma unroll
  for (int kk = 0; kk < 2; ++kk) {
    int c0 = kk * 32 + krow;
    Bh0[kk] = *(const short8_b*)(w2h + d0 * 64 + c0);
    Bl0[kk] = *(const short8_b*)(w2l + d0 * 64 + c0);
    Bh1[kk] = *(const short8_b*)(w2h + d1 * 64 + c0);
    Bl1[kk] = *(const short8_b*)(w2l + d1 * 64 + c0);
  }
  const float bv0 = b2[d0], scv0 = s2[d0], shv0 = s2[128 + d0];
  const float bv1 = b2[d1], scv1 = s2[d1], shv1 = s2[128 + d1];

  __syncthreads();

  for (int m = 0; m < 8; ++m) {
    const int row = m * 16 + col;
    short8_b Ah[2], Al[2];
#pragma unroll
    for (int kk = 0; kk < 2; ++kk) {
      int c0 = kk * 32 + krow;
      Ah[kk] = *(const short8_b*)&zh[row][c0];
      Al[kk] = *(const short8_b*)&zl[row][c0];
    }
    f32x4 acc0 = {0.f, 0.f, 0.f, 0.f};
    f32x4 acc1 = {0.f, 0.f, 0.f, 0.f};
#pragma unroll
    for (int kk = 0; kk < 2; ++kk) {
      acc0 = __builtin_amdgcn_mfma_f32_16x16x32_bf16(Ah[kk], Bh0[kk], acc0, 0, 0, 0);
      acc0 = __builtin_amdgcn_mfma_f32_16x16x32_bf16(Ah[kk], Bl0[kk], acc0, 0, 0, 0);
      acc0 = __builtin_amdgcn_mfma_f32_16x16x32_bf16(Al[kk], Bh0[kk], acc0, 0, 0, 0);
      acc1 = __builtin_amdgcn_mfma_f32_16x16x32_bf16(Ah[kk], Bh1[kk], acc1, 0, 0, 0);
      acc1 = __builtin_amdgcn_mfma_f32_16x16x32_bf16(Ah[kk], Bl1[kk], acc1, 0, 0, 0);
      acc1 = __builtin_amdgcn_mfma_f32_16x16x32_bf16(Al[kk], Bh1[kk], acc1, 0, 0, 0);
    }
    const size_t srow = sbase + m * 16 + (lane >> 4) * 4;
#pragma unroll
    for (int i = 0; i < 4; ++i) {
      float o0 = fmaxf(fmaf(scv0, acc0[i] + bv0, shv0), 0.0f);
      float o1 = fmaxf(fmaf(scv1, acc1[i] + bv1, shv1), 0.0f);
      __builtin_nontemporal_store(o0, &out[(srow + i) * 128 + d0]);
      __builtin_nontemporal_store(o1, &out[(srow + i) * 128 + d1]);
    }
  }
}

// ---------------------------------------------------------------------------
extern "C" void kernel_launch(void* const* d_in, const int* in_sizes, int n_in,
                              void* d_out, int out_size, void* d_ws, size_t ws_size,
                              hipStream_t stream)
{
  const float* points  = (const float*)d_in[0];
  const float* queries = (const float*)d_in[1];
  const float* W1      = (const float*)d_in[2];
  const float* b1      = (const float*)d_in[3];
  const float* gamma1  = (const float*)d_in[4];
  const float* beta1   = (const float*)d_in[5];
  const float* W2      = (const float*)d_in[6];
  const float* b2      = (const float*)d_in[7];
  const float* gamma2  = (const float*)d_in[8];
  const float* beta2   = (const float*)d_in[9];

  char* ws = (char*)d_ws;
  float4* G    = (float4*)(ws + OFF_G);
  float*  gmom = (float*)(ws + OFF_GMOM);
  float*  s1   = (float*)(ws + OFF_S1);
  float*  zzp  = (float*)(ws + OFF_ZZP);
  double* zzs  = (double*)(ws + OFF_ZZS);
  float*  s2   = (float*)(ws + OFF_S2);
  ushort* w2h  = (ushort*)(ws + OFF_W2H);
  ushort* w2l  = (ushort*)(ws + OFF_W2L);
  float*  out  = (float*)d_out;

  knn_kernel<<<512, 1024, 0, stream>>>(points, queries, G, gmom);
  stats1_kernel<<<1, 576, 0, stream>>>(gmom, W1, b1, gamma1, beta1, s1);
  zmom_kernel<<<NBLK_ZZ, 256, 0, stream>>>(G, W1, b1, s1, zzp);
  zzred_kernel<<<130, 256, 0, stream>>>(zzp, zzs);
  stats2_kernel<<<128, 64, 0, stream>>>(zzs, W2, b2, gamma2, beta2, s2, w2h, w2l);
  out_kernel<<<4096, 256, 0, stream>>>(G, W1, b1, s1, w2h, w2l, b2, s2, out);
}